// Round 5
// baseline (175.221 us; speedup 1.0000x reference)
//
#include <hip/hip_runtime.h>
#include <cstdint>
#include <cstddef>

typedef __bf16 bf16;
typedef __attribute__((ext_vector_type(4))) __bf16 bf16x4;
typedef __attribute__((ext_vector_type(8))) __bf16 bf16x8;
typedef __attribute__((ext_vector_type(4))) float f32x4;

#define EPS_C 1e-4f
#define SWZ(r) (((r) ^ ((r) >> 2)) & 3)

// ================= K0: weights prep =================
// Whg/Wlg: reduced in_proj (192 x 1024) hi/lo bf16, CHUNK-MAJOR [k/32][n][k%32]
// = exact MFMA B-fragment order (lane(fr,fs) of col n reads 16B at n*32+fs*8).
// Wob: out_proj_w bf16, [dm=1024][i=64] k-contig (B-fragment order for k3).
__global__ __launch_bounds__(256) void k0_prep(const float* __restrict__ Wi,
    const float* __restrict__ Wo, bf16* __restrict__ Whg, bf16* __restrict__ Wlg,
    bf16* __restrict__ Wob)
{
    int idx = blockIdx.x * 256 + threadIdx.x;
    if (idx < 192 * 1024) {
        int n = idx >> 10, k = idx & 1023;
        float w;
        if (n < 64) {
            w = Wi[n * 1024 + k];
        } else if (n < 128) {
            int i = n - 64;
            w = 0.5f * (Wi[(64 + 2 * i) * 1024 + k] + Wi[(65 + 2 * i) * 1024 + k]);
        } else {
            int i = n - 128;
            w = 0.5f * (Wi[(192 + 2 * i) * 1024 + k] + Wi[(193 + 2 * i) * 1024 + k]);
        }
        bf16 h = (bf16)w;
        int dst = (k >> 5) * 6144 + n * 32 + (k & 31);
        Whg[dst] = h;
        Wlg[dst] = (bf16)(w - (float)h);
    } else {
        int j = idx - 192 * 1024;
        if (j < 65536) Wob[j] = (bf16)Wo[j];
    }
}

// ================= K1: conv + split-bf16 MFMA in_proj + SSM + chunk-local scan =================
// 256 threads (4 waves), 4 blocks/CU. Block: 32t x 192n, BK=32, 32 chunks.
// Wave: 32t x 48n (wn = wave id, distinct) -> acc[2][3], 18 MFMA/chunk.
// W fragments: DIRECT global->reg (L2-hot, fragment-ordered), prefetched 1 chunk ahead.
// x: conv'd hi/lo via small dbuf LDS (8 KB). One barrier per chunk.
__global__ __launch_bounds__(256, 4) void k1_convproj(
    const float* __restrict__ x, const float* __restrict__ conv_w,
    const float* __restrict__ conv_b, const float* __restrict__ in_proj_b,
    const float* __restrict__ A_log,
    const bf16* __restrict__ Whg, const bf16* __restrict__ Wlg,
    float* __restrict__ Yp, float* __restrict__ Zp,
    float* __restrict__ Psum, float* __restrict__ Ssum)
{
    __shared__ char smem[27648];
    // xh buf p @ p*2048, xl buf p @ 4096 + p*2048 ; epilogue res/part overlay

    const int tid  = threadIdx.x;
    const int lane = tid & 63;
    const int wn   = tid >> 6;               // wave = n-quarter (distinct!)
    const int fr   = lane & 15, fs = lane >> 4;
    const int b    = blockIdx.x >> 7;
    const int tc   = blockIdx.x & 127;
    const int t0   = tc * 32;

    // conv/staging mapping: thread -> (t-row ct, 4-ch slot cs)
    const int ct = tid >> 3, cs = tid & 7;
    const int gt = t0 + ct;
    const bool zrow = (gt == 4095);          // reference zero-pads last conv row
    const int xwo = ct * 64 + ((((cs >> 1) ^ SWZ(ct)) & 3) << 4) + (cs & 1) * 8;

    int aoff[2];
#pragma unroll
    for (int mi = 0; mi < 2; ++mi) {
        int r = mi * 16 + fr;
        aoff[mi] = r * 64 + ((fs ^ SWZ(r)) << 4);
    }

    bool tapok[4];
#pragma unroll
    for (int dt = 0; dt < 4; ++dt) { int g = gt - 1 + dt; tapok[dt] = (g >= 0) && (g < 4096); }

    f32x4  xr[4];
    bf16x8 wfh[3], wfl[3];

    // W fragment base: lane's 16B within chunk = (col)*32 + fs*8, col = wn*48 + ni*16 + fr
    const size_t wfo = (size_t)(wn * 48 + fr) * 32 + fs * 8;

    auto fetch_x = [&](int c) {
        const int ch0 = c * 32 + cs * 4;
#pragma unroll
        for (int dt = 0; dt < 4; ++dt) {
            int g = gt - 1 + dt;
            size_t row = (size_t)(tapok[dt] ? g : 0);
            f32x4 v = *(const f32x4*)&x[((size_t)b * 4096 + row) * 1024 + ch0];
            f32x4 z = {0.f, 0.f, 0.f, 0.f};
            xr[dt] = tapok[dt] ? v : z;
        }
    };
    auto fetch_w = [&](int c) {
        const bf16* ph = Whg + (size_t)c * 6144 + wfo;
        const bf16* pl = Wlg + (size_t)c * 6144 + wfo;
#pragma unroll
        for (int ni = 0; ni < 3; ++ni) {
            wfh[ni] = *(const bf16x8*)(ph + ni * 512);
            wfl[ni] = *(const bf16x8*)(pl + ni * 512);
        }
    };
    auto stage = [&](int c, int p) {         // conv chunk c from xr -> LDS buf p
        char* xh = smem + p * 2048;
        char* xl = smem + 4096 + p * 2048;
        const int ch0 = c * 32 + cs * 4;
        bf16x4 hi, lo;
#pragma unroll
        for (int j = 0; j < 4; ++j) {
            float v = 0.f;
            if (!zrow) {
                f32x4 cw = *(const f32x4*)&conv_w[(ch0 + j) * 4];   // L1-hot
                v = conv_b[ch0 + j];
                v = fmaf(cw.x, xr[0][j], v);
                v = fmaf(cw.y, xr[1][j], v);
                v = fmaf(cw.z, xr[2][j], v);
                v = fmaf(cw.w, xr[3][j], v);
            }
            bf16 h = (bf16)v;
            hi[j] = h;
            lo[j] = (bf16)(v - (float)h);
        }
        *(bf16x4*)(xh + xwo) = hi;
        *(bf16x4*)(xl + xwo) = lo;
    };

    f32x4 acc[2][3] = {};

    fetch_x(0);
    fetch_w(0);
    stage(0, 0);
    fetch_x(1);
    __syncthreads();

#pragma unroll 1
    for (int c = 0; c < 32; ++c) {
        const int p = c & 1;
        const char* xh = smem + p * 2048;
        const char* xl = smem + 4096 + p * 2048;
        bf16x8 ah0 = *(const bf16x8*)(xh + aoff[0]);
        bf16x8 ah1 = *(const bf16x8*)(xh + aoff[1]);
        bf16x8 al0 = *(const bf16x8*)(xl + aoff[0]);
        bf16x8 al1 = *(const bf16x8*)(xl + aoff[1]);
#pragma unroll
        for (int ni = 0; ni < 3; ++ni) {
            bf16x8 bh = wfh[ni], bl = wfl[ni];
            acc[0][ni] = __builtin_amdgcn_mfma_f32_16x16x32_bf16(ah0, bh, acc[0][ni], 0, 0, 0);
            acc[1][ni] = __builtin_amdgcn_mfma_f32_16x16x32_bf16(ah1, bh, acc[1][ni], 0, 0, 0);
            acc[0][ni] = __builtin_amdgcn_mfma_f32_16x16x32_bf16(al0, bh, acc[0][ni], 0, 0, 0);
            acc[1][ni] = __builtin_amdgcn_mfma_f32_16x16x32_bf16(al1, bh, acc[1][ni], 0, 0, 0);
            acc[0][ni] = __builtin_amdgcn_mfma_f32_16x16x32_bf16(ah0, bl, acc[0][ni], 0, 0, 0);
            acc[1][ni] = __builtin_amdgcn_mfma_f32_16x16x32_bf16(ah1, bl, acc[1][ni], 0, 0, 0);
        }
        if (c < 31) {
            fetch_w(c + 1);                  // regs free after MFMA; full-chunk distance
            stage(c + 1, p ^ 1);             // conv from xr = x(c+1)
            if (c < 30) fetch_x(c + 2);      // full-chunk distance to conv
        }
        __syncthreads();
    }

    // ---- epilogue: acc -> res[32][196], SSM elementwise + chunk-local scan ----
    float* res = (float*)smem;
#pragma unroll
    for (int mi = 0; mi < 2; ++mi)
#pragma unroll
        for (int ni = 0; ni < 3; ++ni) {
            int col = wn * 48 + ni * 16 + fr;
#pragma unroll
            for (int r = 0; r < 4; ++r)
                res[(mi * 16 + fs * 4 + r) * 196 + col] = acc[mi][ni][r];
        }
    __syncthreads();

    float* part = (float*)(smem + 25088);    // [2][4][64]
    const int i  = lane;
    const int tg = tid >> 6;
    const float A  = -expf(A_log[i]);
    const float bd = in_proj_b[i];
    const float bB = 0.5f * (in_proj_b[64 + 2 * i] + in_proj_b[65 + 2 * i]);
    const float bC = 0.5f * (in_proj_b[192 + 2 * i] + in_proj_b[193 + 2 * i]);
    const bool tiny = fabsf(A) < EPS_C;
    float av[8], bv[8], cv[8];
#pragma unroll
    for (int r = 0; r < 8; ++r) {
        int t = tg * 8 + r;
        float d  = res[t * 196 + i] + bd;
        float Bm = res[t * 196 + 64 + i] + bB;
        float Cm = res[t * 196 + 128 + i] + bC;
        float delta = (d > 20.f) ? d : log1pf(expf(d));
        float dA = delta * A;
        float abar = expf(dA);
        float sc = tiny ? (1.f + dA * 0.5f + dA * dA * (1.f / 6.f)) : ((abar - 1.f) / A);
        av[r] = abar; bv[r] = sc * Bm; cv[r] = Cm;
    }
    float P = 1.f, S = 0.f;
#pragma unroll
    for (int r = 0; r < 8; ++r) { S = fmaf(av[r], S, bv[r]); P *= av[r]; }
    part[tg * 64 + i] = P;
    part[256 + tg * 64 + i] = S;
    __syncthreads();
    float h = 0.f, pp = 1.f;
#pragma unroll
    for (int g = 0; g < 3; ++g)
        if (g < tg) {
            float Pg = part[g * 64 + i], Sg = part[256 + g * 64 + i];
            h = fmaf(Pg, h, Sg);
            pp *= Pg;
        }
    size_t ob = ((size_t)b * 4096 + t0 + tg * 8) * 64 + i;
#pragma unroll
    for (int r = 0; r < 8; ++r) {
        h  = fmaf(av[r], h, bv[r]);          // chunk-local state
        pp *= av[r];                          // chunk-local prefix product
        Yp[ob + (size_t)r * 64] = cv[r] * h;
        Zp[ob + (size_t)r * 64] = cv[r] * pp;
    }
    if (tg == 3) {
        size_t o = ((size_t)b * 128 + tc) * 64 + i;
        Psum[o] = pp;
        Ssum[o] = h;
    }
}

// ================= K2: serial carry combine across 128 chunks =================
__global__ __launch_bounds__(64) void k2_scan2(const float* __restrict__ Psum,
    const float* __restrict__ Ssum, float* __restrict__ Carry)
{
    int b = blockIdx.x, i = threadIdx.x;
    float h = 0.f;
#pragma unroll 1
    for (int g = 0; g < 8; ++g) {
        size_t base = ((size_t)b * 128 + g * 16) * 64 + i;
        float Pv[16], Sv[16];
#pragma unroll
        for (int j = 0; j < 16; ++j) {
            Pv[j] = Psum[base + (size_t)j * 64];
            Sv[j] = Ssum[base + (size_t)j * 64];
        }
#pragma unroll
        for (int j = 0; j < 16; ++j) {
            Carry[base + (size_t)j * 64] = h;
            h = fmaf(Pv[j], h, Sv[j]);
        }
    }
}

// ================= K3: y = Yp + Zp*carry, fused out_proj MFMA =================
// 512 threads (8 waves). Block = 32-t chunk; wave: 32t x 128n.
__global__ __launch_bounds__(512) void k3_scan_out(
    const float* __restrict__ Yp, const float* __restrict__ Zp,
    const float* __restrict__ Carry, const bf16* __restrict__ Wob,
    const float* __restrict__ bo, float* __restrict__ out)
{
    __shared__ char sm3[4096];               // [32 t][64 i] bf16, swizzled 128B rows

    const int tid  = threadIdx.x;
    const int lane = tid & 63;
    const int wv   = tid >> 6;
    const int b    = blockIdx.x >> 7;
    const int ch   = blockIdx.x & 127;
    const int t0   = ch * 32;

    const int i = lane, tg = wv;
    float cr = Carry[((size_t)b * 128 + ch) * 64 + i];
    size_t base = ((size_t)b * 4096 + t0 + tg * 4) * 64 + i;
#pragma unroll
    for (int r = 0; r < 4; ++r) {
        float y = Yp[base + (size_t)r * 64] + Zp[base + (size_t)r * 64] * cr;
        int t = tg * 4 + r;
        int off = t * 128 + ((((i >> 3) ^ (t & 7)) & 7) << 4) + (i & 7) * 2;
        *(bf16*)(sm3 + off) = (bf16)y;
    }
    __syncthreads();

    const int fr = lane & 15, fs = lane >> 4;
    bf16x8 afr[2][2];
#pragma unroll
    for (int mi = 0; mi < 2; ++mi)
#pragma unroll
        for (int ks = 0; ks < 2; ++ks) {
            int row = mi * 16 + fr;
            int slot = ks * 4 + fs;
            int off = row * 128 + (((slot ^ (row & 7)) & 7) << 4);
            afr[mi][ks] = *(const bf16x8*)(sm3 + off);
        }
    const int n0 = wv * 128;
#pragma unroll
    for (int ni = 0; ni < 8; ++ni) {
        int col = n0 + ni * 16 + fr;
        bf16x8 b0 = *(const bf16x8*)(Wob + (size_t)col * 64 + fs * 8);
        bf16x8 b1 = *(const bf16x8*)(Wob + (size_t)col * 64 + 32 + fs * 8);
        float bias = bo[col];
#pragma unroll
        for (int mi = 0; mi < 2; ++mi) {
            f32x4 a = {};
            a = __builtin_amdgcn_mfma_f32_16x16x32_bf16(afr[mi][0], b0, a, 0, 0, 0);
            a = __builtin_amdgcn_mfma_f32_16x16x32_bf16(afr[mi][1], b1, a, 0, 0, 0);
#pragma unroll
            for (int r = 0; r < 4; ++r) {
                int t = mi * 16 + fs * 4 + r;
                out[((size_t)b * 4096 + t0 + t) * 1024 + col] = a[r] + bias;
            }
        }
    }
}

extern "C" void kernel_launch(void* const* d_in, const int* in_sizes, int n_in,
                              void* d_out, int out_size, void* d_ws, size_t ws_size,
                              hipStream_t stream) {
    const float* x          = (const float*)d_in[0];
    const float* conv_w     = (const float*)d_in[1];
    const float* conv_b     = (const float*)d_in[2];
    const float* in_proj_w  = (const float*)d_in[3];
    const float* in_proj_b  = (const float*)d_in[4];
    const float* A_log      = (const float*)d_in[5];
    const float* out_proj_w = (const float*)d_in[6];
    const float* out_proj_b = (const float*)d_in[7];
    float* out = (float*)d_out;

    char* w = (char*)d_ws;
    bf16*  Whg  = (bf16*)w;                                   // 393216 B
    bf16*  Wlg  = (bf16*)(w + 393216);                        // 393216 B
    bf16*  Wob  = (bf16*)(w + 786432);                        // 131072 B
    float* Yp   = (float*)(w + 917504);                       // 8 MiB
    float* Zp   = (float*)(w + 917504 + 8388608);             // 8 MiB
    float* Psum = (float*)(w + 917504 + 2 * 8388608);         // 256 KiB
    float* Ssum = (float*)(w + 917504 + 2 * 8388608 + 262144);
    float* Carry= (float*)(w + 917504 + 2 * 8388608 + 524288);

    hipLaunchKernelGGL(k0_prep,     dim3(1024), dim3(256), 0, stream,
                       in_proj_w, out_proj_w, Whg, Wlg, Wob);
    hipLaunchKernelGGL(k1_convproj, dim3(1024), dim3(256), 0, stream,
                       x, conv_w, conv_b, in_proj_b, A_log, Whg, Wlg,
                       Yp, Zp, Psum, Ssum);
    hipLaunchKernelGGL(k2_scan2,    dim3(8),    dim3(64),  0, stream, Psum, Ssum, Carry);
    hipLaunchKernelGGL(k3_scan_out, dim3(1024), dim3(512), 0, stream,
                       Yp, Zp, Carry, Wob, out_proj_b, out);
}

// Round 6
// 128.030 us; speedup vs baseline: 1.3686x; 1.3686x over previous
//
#include <hip/hip_runtime.h>
#include <cstdint>
#include <cstddef>

typedef __bf16 bf16;
typedef __attribute__((ext_vector_type(4))) __bf16 bf16x4;
typedef __attribute__((ext_vector_type(8))) __bf16 bf16x8;
typedef __attribute__((ext_vector_type(4))) float f32x4;

#define EPS_C 1e-4f
#define SWZ(r) (((r) ^ ((r) >> 2)) & 3)

// light barrier: LDS visibility only, vmem loads stay in flight (no vmcnt drain)
#define BAR_LDS() do { asm volatile("s_waitcnt lgkmcnt(0)" ::: "memory"); \
                       __builtin_amdgcn_s_barrier(); } while (0)

// ================= K0: weights prep + zero page =================
// Whg/Wlg: reduced in_proj (192 x 1024) hi/lo bf16, CHUNK-MAJOR [k/32][n][k%32]
// = exact MFMA B-fragment order. Wob: out_proj_w bf16 [dm][i].
__global__ __launch_bounds__(256) void k0_prep(const float* __restrict__ Wi,
    const float* __restrict__ Wo, bf16* __restrict__ Whg, bf16* __restrict__ Wlg,
    bf16* __restrict__ Wob, float* __restrict__ zpg)
{
    int idx = blockIdx.x * 256 + threadIdx.x;
    if (idx < 192 * 1024) {
        int n = idx >> 10, k = idx & 1023;
        float w;
        if (n < 64) {
            w = Wi[n * 1024 + k];
        } else if (n < 128) {
            int i = n - 64;
            w = 0.5f * (Wi[(64 + 2 * i) * 1024 + k] + Wi[(65 + 2 * i) * 1024 + k]);
        } else {
            int i = n - 128;
            w = 0.5f * (Wi[(192 + 2 * i) * 1024 + k] + Wi[(193 + 2 * i) * 1024 + k]);
        }
        bf16 h = (bf16)w;
        int dst = (k >> 5) * 6144 + n * 32 + (k & 31);
        Whg[dst] = h;
        Wlg[dst] = (bf16)(w - (float)h);
    } else if (idx < 262144) {
        int j = idx - 192 * 1024;
        Wob[j] = (bf16)Wo[j];
    } else {
        int j = idx - 262144;
        if (j < 512) { f32x4 z = {0.f, 0.f, 0.f, 0.f}; ((f32x4*)zpg)[j] = z; }
    }
}

// ================= K1: conv + split-bf16 MFMA in_proj + SSM + chunk-local scan =================
// 256 threads (4 waves), 4 blocks/CU. Block: 32t x 192n, BK=32, 32 chunks.
// Wave: 32t x 48n (wn = wave id). W fragments direct global->reg (fragment-ordered).
// Light barrier keeps prefetches in flight; conv tables live in LDS.
__global__ __launch_bounds__(256, 4) void k1_convproj(
    const float* __restrict__ x, const float* __restrict__ conv_w,
    const float* __restrict__ conv_b, const float* __restrict__ in_proj_b,
    const float* __restrict__ A_log,
    const bf16* __restrict__ Whg, const bf16* __restrict__ Wlg,
    const float* __restrict__ zpg,
    float* __restrict__ Yp, float* __restrict__ Zp,
    float* __restrict__ Psum, float* __restrict__ Ssum)
{
    __shared__ char smem[28672];
    // [0,2048) xh buf0 | [2048,4096) xh buf1 | [4096,6144) xl buf0 | [6144,8192) xl buf1
    // [8192,24576) cwT[4][1024] f32 (tap-major) | [24576,28672) cbl[1024] f32
    // epilogue overlay: res[32][196] f32 @0 (25088 B), part @25088 (2048 B)

    const int tid  = threadIdx.x;
    const int lane = tid & 63;
    const int wn   = tid >> 6;
    const int fr   = lane & 15, fs = lane >> 4;
    const int b    = blockIdx.x >> 7;
    const int tc   = blockIdx.x & 127;
    const int t0   = tc * 32;

    // staging mapping: thread -> (t-row ct, 4-ch slot cs)
    const int ct = tid >> 3, cs = tid & 7;
    const int gt = t0 + ct;
    const bool zrow = (gt == 4095);          // reference zero-pads last conv row
    const int xwo = ct * 64 + ((((cs >> 1) ^ SWZ(ct)) & 3) << 4) + (cs & 1) * 8;

    int aoff[2];
#pragma unroll
    for (int mi = 0; mi < 2; ++mi) {
        int r = mi * 16 + fr;
        aoff[mi] = r * 64 + ((fs ^ SWZ(r)) << 4);
    }

    // per-tap x pointers (OOB taps -> zero page); chunk offset is load-immediate
    const float* xp[4];
#pragma unroll
    for (int dt = 0; dt < 4; ++dt) {
        int g = gt - 1 + dt;
        xp[dt] = (g >= 0 && g < 4096) ? (x + ((size_t)b * 4096 + g) * 1024 + cs * 4)
                                      : (zpg + cs * 4);
    }

    // W fragment pointers (running, bumped per chunk)
    const size_t wfo = (size_t)(wn * 48 + fr) * 32 + fs * 8;
    const bf16* ph = Whg + wfo;
    const bf16* pl = Wlg + wfo;

    // ---- preload conv tables to LDS (tap-major: conflict-free f32x4 reads) ----
    {
        float* cwT = (float*)(smem + 8192);
        float* cbl = (float*)(smem + 24576);
        for (int p = tid; p < 1024; p += 256) {
            f32x4 w4 = *(const f32x4*)&conv_w[p * 4];
            cwT[p]        = w4.x;
            cwT[1024 + p] = w4.y;
            cwT[2048 + p] = w4.z;
            cwT[3072 + p] = w4.w;
        }
        ((f32x4*)cbl)[tid] = ((const f32x4*)conv_b)[tid];
    }

    f32x4  xr[4];
    bf16x8 wfh[3], wfl[3];
    f32x4  acc[2][3] = {};

    auto fetch_x = [&](int c) {
#pragma unroll
        for (int dt = 0; dt < 4; ++dt)
            xr[dt] = *(const f32x4*)(xp[dt] + c * 32);
    };
    auto fetch_w = [&]() {                   // loads from current ph/pl
#pragma unroll
        for (int ni = 0; ni < 3; ++ni) {
            wfh[ni] = *(const bf16x8*)(ph + ni * 512);
            wfl[ni] = *(const bf16x8*)(pl + ni * 512);
        }
    };
    auto stage = [&](int c, int p) {         // conv chunk c from xr -> LDS buf p
        char* xh = smem + p * 2048;
        char* xl = smem + 4096 + p * 2048;
        const float* cwT = (const float*)(smem + 8192);
        const float* cbl = (const float*)(smem + 24576);
        const int ch0 = c * 32 + cs * 4;     // LDS imm-friendly offsets
        f32x4 w0 = *(const f32x4*)&cwT[ch0];
        f32x4 w1 = *(const f32x4*)&cwT[1024 + ch0];
        f32x4 w2 = *(const f32x4*)&cwT[2048 + ch0];
        f32x4 w3 = *(const f32x4*)&cwT[3072 + ch0];
        f32x4 bb = *(const f32x4*)&cbl[ch0];
        bf16x4 hi, lo;
#pragma unroll
        for (int j = 0; j < 4; ++j) {
            float v = bb[j];
            v = fmaf(w0[j], xr[0][j], v);
            v = fmaf(w1[j], xr[1][j], v);
            v = fmaf(w2[j], xr[2][j], v);
            v = fmaf(w3[j], xr[3][j], v);
            v = zrow ? 0.f : v;
            bf16 h = (bf16)v;
            hi[j] = h;
            lo[j] = (bf16)(v - (float)h);
        }
        *(bf16x4*)(xh + xwo) = hi;
        *(bf16x4*)(xl + xwo) = lo;
    };

    // ---- prologue ----
    fetch_x(0);
    fetch_w();                               // W(0)
    __syncthreads();                         // conv tables visible
    stage(0, 0);
    fetch_x(1);                              // x(1) for stage(1)
    __syncthreads();                         // buf0 visible

    auto body = [&](int c, int par) {
        const char* xh = smem + par * 2048;
        const char* xl = smem + 4096 + par * 2048;
        bf16x8 ah0 = *(const bf16x8*)(xh + aoff[0]);
        bf16x8 ah1 = *(const bf16x8*)(xh + aoff[1]);
        bf16x8 al0 = *(const bf16x8*)(xl + aoff[0]);
        bf16x8 al1 = *(const bf16x8*)(xl + aoff[1]);
#pragma unroll
        for (int ni = 0; ni < 3; ++ni) {
            bf16x8 bh = wfh[ni], bl = wfl[ni];
            acc[0][ni] = __builtin_amdgcn_mfma_f32_16x16x32_bf16(ah0, bh, acc[0][ni], 0, 0, 0);
            acc[1][ni] = __builtin_amdgcn_mfma_f32_16x16x32_bf16(ah1, bh, acc[1][ni], 0, 0, 0);
            acc[0][ni] = __builtin_amdgcn_mfma_f32_16x16x32_bf16(al0, bh, acc[0][ni], 0, 0, 0);
            acc[1][ni] = __builtin_amdgcn_mfma_f32_16x16x32_bf16(al1, bh, acc[1][ni], 0, 0, 0);
            acc[0][ni] = __builtin_amdgcn_mfma_f32_16x16x32_bf16(ah0, bl, acc[0][ni], 0, 0, 0);
            acc[1][ni] = __builtin_amdgcn_mfma_f32_16x16x32_bf16(ah1, bl, acc[1][ni], 0, 0, 0);
        }
        if (c + 1 < 32) {
            ph += 6144; pl += 6144;
            fetch_w();                       // W(c+1): in flight across barrier
            stage(c + 1, par ^ 1);           // conv of x(c+1) (regs), write other buf
            if (c + 2 < 32) fetch_x(c + 2);  // x(c+2): in flight across barrier
        }
        BAR_LDS();                           // NO vmcnt drain
    };

#pragma unroll 1
    for (int cc = 0; cc < 32; cc += 2) {
        body(cc,     0);
        body(cc + 1, 1);
    }

    // ---- epilogue: acc -> res[32][196], SSM elementwise + chunk-local scan ----
    float* res = (float*)smem;
#pragma unroll
    for (int mi = 0; mi < 2; ++mi)
#pragma unroll
        for (int ni = 0; ni < 3; ++ni) {
            int col = wn * 48 + ni * 16 + fr;
#pragma unroll
            for (int r = 0; r < 4; ++r)
                res[(mi * 16 + fs * 4 + r) * 196 + col] = acc[mi][ni][r];
        }
    __syncthreads();

    float* part = (float*)(smem + 25088);    // [2][4][64]
    const int i  = lane;
    const int tg = tid >> 6;
    const float A  = -expf(A_log[i]);
    const float bd = in_proj_b[i];
    const float bB = 0.5f * (in_proj_b[64 + 2 * i] + in_proj_b[65 + 2 * i]);
    const float bC = 0.5f * (in_proj_b[192 + 2 * i] + in_proj_b[193 + 2 * i]);
    const bool tiny = fabsf(A) < EPS_C;
    float av[8], bv[8], cv[8];
#pragma unroll
    for (int r = 0; r < 8; ++r) {
        int t = tg * 8 + r;
        float d  = res[t * 196 + i] + bd;
        float Bm = res[t * 196 + 64 + i] + bB;
        float Cm = res[t * 196 + 128 + i] + bC;
        float delta = (d > 20.f) ? d : log1pf(expf(d));
        float dA = delta * A;
        float abar = expf(dA);
        float sc = tiny ? (1.f + dA * 0.5f + dA * dA * (1.f / 6.f)) : ((abar - 1.f) / A);
        av[r] = abar; bv[r] = sc * Bm; cv[r] = Cm;
    }
    float P = 1.f, S = 0.f;
#pragma unroll
    for (int r = 0; r < 8; ++r) { S = fmaf(av[r], S, bv[r]); P *= av[r]; }
    part[tg * 64 + i] = P;
    part[256 + tg * 64 + i] = S;
    __syncthreads();
    float h = 0.f, pp = 1.f;
#pragma unroll
    for (int g = 0; g < 3; ++g)
        if (g < tg) {
            float Pg = part[g * 64 + i], Sg = part[256 + g * 64 + i];
            h = fmaf(Pg, h, Sg);
            pp *= Pg;
        }
    size_t ob = ((size_t)b * 4096 + t0 + tg * 8) * 64 + i;
#pragma unroll
    for (int r = 0; r < 8; ++r) {
        h  = fmaf(av[r], h, bv[r]);          // chunk-local state
        pp *= av[r];                         // chunk-local prefix product
        Yp[ob + (size_t)r * 64] = cv[r] * h;
        Zp[ob + (size_t)r * 64] = cv[r] * pp;
    }
    if (tg == 3) {
        size_t o = ((size_t)b * 128 + tc) * 64 + i;
        Psum[o] = pp;
        Ssum[o] = h;
    }
}

// ================= K2: serial carry combine across 128 chunks =================
__global__ __launch_bounds__(64) void k2_scan2(const float* __restrict__ Psum,
    const float* __restrict__ Ssum, float* __restrict__ Carry)
{
    int b = blockIdx.x, i = threadIdx.x;
    float h = 0.f;
#pragma unroll 1
    for (int g = 0; g < 8; ++g) {
        size_t base = ((size_t)b * 128 + g * 16) * 64 + i;
        float Pv[16], Sv[16];
#pragma unroll
        for (int j = 0; j < 16; ++j) {
            Pv[j] = Psum[base + (size_t)j * 64];
            Sv[j] = Ssum[base + (size_t)j * 64];
        }
#pragma unroll
        for (int j = 0; j < 16; ++j) {
            Carry[base + (size_t)j * 64] = h;
            h = fmaf(Pv[j], h, Sv[j]);
        }
    }
}

// ================= K3: y = Yp + Zp*carry, fused out_proj MFMA =================
__global__ __launch_bounds__(512) void k3_scan_out(
    const float* __restrict__ Yp, const float* __restrict__ Zp,
    const float* __restrict__ Carry, const bf16* __restrict__ Wob,
    const float* __restrict__ bo, float* __restrict__ out)
{
    __shared__ char sm3[4096];               // [32 t][64 i] bf16, swizzled

    const int tid  = threadIdx.x;
    const int lane = tid & 63;
    const int wv   = tid >> 6;
    const int b    = blockIdx.x >> 7;
    const int ch   = blockIdx.x & 127;
    const int t0   = ch * 32;

    const int i = lane, tg = wv;
    float cr = Carry[((size_t)b * 128 + ch) * 64 + i];
    size_t base = ((size_t)b * 4096 + t0 + tg * 4) * 64 + i;
#pragma unroll
    for (int r = 0; r < 4; ++r) {
        float y = Yp[base + (size_t)r * 64] + Zp[base + (size_t)r * 64] * cr;
        int t = tg * 4 + r;
        int off = t * 128 + ((((i >> 3) ^ (t & 7)) & 7) << 4) + (i & 7) * 2;
        *(bf16*)(sm3 + off) = (bf16)y;
    }
    __syncthreads();

    const int fr = lane & 15, fs = lane >> 4;
    bf16x8 afr[2][2];
#pragma unroll
    for (int mi = 0; mi < 2; ++mi)
#pragma unroll
        for (int ks = 0; ks < 2; ++ks) {
            int row = mi * 16 + fr;
            int slot = ks * 4 + fs;
            int off = row * 128 + (((slot ^ (row & 7)) & 7) << 4);
            afr[mi][ks] = *(const bf16x8*)(sm3 + off);
        }
    const int n0 = wv * 128;
#pragma unroll
    for (int ni = 0; ni < 8; ++ni) {
        int col = n0 + ni * 16 + fr;
        bf16x8 b0 = *(const bf16x8*)(Wob + (size_t)col * 64 + fs * 8);
        bf16x8 b1 = *(const bf16x8*)(Wob + (size_t)col * 64 + 32 + fs * 8);
        float bias = bo[col];
#pragma unroll
        for (int mi = 0; mi < 2; ++mi) {
            f32x4 a = {};
            a = __builtin_amdgcn_mfma_f32_16x16x32_bf16(afr[mi][0], b0, a, 0, 0, 0);
            a = __builtin_amdgcn_mfma_f32_16x16x32_bf16(afr[mi][1], b1, a, 0, 0, 0);
#pragma unroll
            for (int r = 0; r < 4; ++r) {
                int t = mi * 16 + fs * 4 + r;
                out[((size_t)b * 4096 + t0 + t) * 1024 + col] = a[r] + bias;
            }
        }
    }
}

extern "C" void kernel_launch(void* const* d_in, const int* in_sizes, int n_in,
                              void* d_out, int out_size, void* d_ws, size_t ws_size,
                              hipStream_t stream) {
    const float* x          = (const float*)d_in[0];
    const float* conv_w     = (const float*)d_in[1];
    const float* conv_b     = (const float*)d_in[2];
    const float* in_proj_w  = (const float*)d_in[3];
    const float* in_proj_b  = (const float*)d_in[4];
    const float* A_log      = (const float*)d_in[5];
    const float* out_proj_w = (const float*)d_in[6];
    const float* out_proj_b = (const float*)d_in[7];
    float* out = (float*)d_out;

    char* w = (char*)d_ws;
    bf16*  Whg  = (bf16*)w;                                   // 393216 B
    bf16*  Wlg  = (bf16*)(w + 393216);                        // 393216 B
    bf16*  Wob  = (bf16*)(w + 786432);                        // 131072 B
    float* Yp   = (float*)(w + 917504);                       // 8 MiB
    float* Zp   = (float*)(w + 917504 + 8388608);             // 8 MiB
    float* Psum = (float*)(w + 917504 + 2 * 8388608);         // 256 KiB
    float* Ssum = (float*)(w + 917504 + 2 * 8388608 + 262144);
    float* Carry= (float*)(w + 917504 + 2 * 8388608 + 524288);
    float* zpg  = (float*)(w + 917504 + 2 * 8388608 + 786432); // 8 KiB zero page

    hipLaunchKernelGGL(k0_prep,     dim3(1025), dim3(256), 0, stream,
                       in_proj_w, out_proj_w, Whg, Wlg, Wob, zpg);
    hipLaunchKernelGGL(k1_convproj, dim3(1024), dim3(256), 0, stream,
                       x, conv_w, conv_b, in_proj_b, A_log, Whg, Wlg, zpg,
                       Yp, Zp, Psum, Ssum);
    hipLaunchKernelGGL(k2_scan2,    dim3(8),    dim3(64),  0, stream, Psum, Ssum, Carry);
    hipLaunchKernelGGL(k3_scan_out, dim3(1024), dim3(512), 0, stream,
                       Yp, Zp, Carry, Wob, out_proj_b, out);
}